// Round 2
// baseline (404.125 us; speedup 1.0000x reference)
//
#include <hip/hip_runtime.h>

// Gather3d sparse-mode constants (from reference)
#define C_DIM 128
#define T_DIM 16
#define H_DIM 128
#define W_DIM 128
#define PAD_T 2
#define TT (T_DIM + PAD_T)           // 18 output planes per (n,c)

// LDS plane layout: row stride 144 floats. 144 % 32 == 16 -> the inner-loop
// read footprint covers all 32 banks evenly (adjacent rows land 16 banks
// apart). 128*144*4 = 73,728 B -> 2 workgroups / CU.
#define S_LDS 144
#define PLANE_F (H_DIM * S_LDS)      // 18432 floats
#define MAX_N 256                    // idx LDS capacity (harness: N=128)

typedef float f4  __attribute__((ext_vector_type(4), aligned(16)));
typedef float f4l __attribute__((ext_vector_type(4), aligned(4)));  // LDS read at runtime 4B offset

__global__ __launch_bounds__(256, 2) void gather3d_plane(
    const float* __restrict__ x,          // [C, T, H, W]
    const int*   __restrict__ active_idx, // [N, 2]
    float*       __restrict__ out,        // [N, C, TT, 16, 16]
    int N)
{
    __shared__ float plane[PLANE_F];
    __shared__ int   idx_s[2 * MAX_N];

    const int c   = blockIdx.x;           // channel
    const int tt  = blockIdx.y;           // output time plane 0..17
    const int tid = threadIdx.x;

    // Stage indices once: inner-loop idx reads become uniform-address LDS
    // broadcasts instead of per-iteration s_load latency chains.
    for (int i = tid; i < 2 * N && i < 2 * MAX_N; i += 256) idx_s[i] = active_idx[i];

    if (tt >= PAD_T) {
        // Stage the full 128x128 plane x[c][tt-2] into LDS: dense float4
        // loads, x read exactly once, fully coalesced.
        const float* __restrict__ src =
            x + ((size_t)c * T_DIM + (size_t)(tt - PAD_T)) * (size_t)(H_DIM * W_DIM);
        #pragma unroll
        for (int it = 0; it < (H_DIM * W_DIM) / (256 * 4); ++it) {  // 16 iters
            const int f   = (it * 256 + tid) * 4;   // float index in plane
            const int r   = f >> 7;                 // 0..127
            const int col = f & 127;                // multiple of 4 -> 16B aligned
            *(f4*)(&plane[r * S_LDS + col]) = *(const f4*)(src + f);
        }
    }
    __syncthreads();

    // Wave w handles n = w, w+4, w+8, ... ; its 64 lanes cover the 16x16
    // block as (row = slot>>2, 4 cols starting at (slot&3)*4).
    // Per iteration per wave: 1 uniform LDS idx read + 1 float4 LDS read +
    // 1 global_store_dwordx4 (64 lanes x 16B = 1KB contiguous).
    const int wid  = tid >> 6;
    const int slot = tid & 63;
    const int row  = slot >> 2;
    const int cg   = (slot & 3) << 2;     // column group start: 0,4,8,12

    float* opbase = out + ((size_t)c * TT + tt) * 256 + row * 16 + cg;
    const size_t nstride = (size_t)C_DIM * TT * 256;   // out stride between n's

    if (tt >= PAD_T) {
        const float* pl = plane + row * S_LDS + cg;
        #pragma unroll 8
        for (int n = wid; n < N; n += 4) {
            const int i0 = idx_s[2 * n];      // wave-uniform -> LDS broadcast
            const int i1 = idx_s[2 * n + 1];
            f4 v = *(const f4l*)(pl + i0 * S_LDS + i1);   // 4B-aligned float4
            __builtin_nontemporal_store(v, (f4*)(opbase + (size_t)n * nstride));
        }
    } else {
        // tt < PAD_T: causal time padding -> zero planes.
        const f4 z = {0.f, 0.f, 0.f, 0.f};
        #pragma unroll 8
        for (int n = wid; n < N; n += 4) {
            __builtin_nontemporal_store(z, (f4*)(opbase + (size_t)n * nstride));
        }
    }
}

extern "C" void kernel_launch(void* const* d_in, const int* in_sizes, int n_in,
                              void* d_out, int out_size, void* d_ws, size_t ws_size,
                              hipStream_t stream) {
    const float* x   = (const float*)d_in[0];
    const int*   idx = (const int*)d_in[1];
    float*       out = (float*)d_out;

    const int N = in_sizes[1] / 2;   // 128 active indices

    dim3 grid(C_DIM, TT);            // one workgroup per (c, tt) plane
    gather3d_plane<<<grid, dim3(256), 0, stream>>>(x, idx, out, N);
}

// Round 3
// 402.243 us; speedup vs baseline: 1.0047x; 1.0047x over previous
//
#include <hip/hip_runtime.h>

// Gather3d sparse-mode constants (from reference)
#define C_DIM 128
#define T_DIM 16
#define H_DIM 128
#define W_DIM 128
#define PAD_T 2
#define TT (T_DIM + PAD_T)           // 18 output planes per (n,c)

// LDS plane layout: row stride 144 floats. 144 % 32 == 16 -> a wave's
// 16-row x 16-col f4 read footprint covers all 32 banks exactly evenly
// (verified: (16*parity(row) + col) spans 32 banks, 8 dwords/bank = the
// b128 minimum). 128*144*4 = 73,728 B -> 2 workgroups / CU.
#define S_LDS 144
#define PLANE_F (H_DIM * S_LDS)      // 18432 floats
#define MAX_N 256                    // idx LDS capacity (harness: N=128)

#define NTHREADS 1024
#define NWAVES (NTHREADS / 64)       // 16

typedef float f4  __attribute__((ext_vector_type(4), aligned(16)));
typedef float f4l __attribute__((ext_vector_type(4), aligned(4)));  // LDS read at runtime 4B offset

// 1024 threads, min 8 waves/SIMD -> VGPR capped at 64 so TWO 1024-thread
// workgroups (32 waves) fit per CU. Previous 256-thread version ran at only
// 8 waves/CU: staging had 16KB in flight vs ~900cyc cold-HBM latency
// (~4.5 B/cyc/CU, half the per-CU HBM share) -> latency-bound.
__global__ __launch_bounds__(NTHREADS, 8) void gather3d_plane(
    const float* __restrict__ x,          // [C, T, H, W]
    const int*   __restrict__ active_idx, // [N, 2]
    float*       __restrict__ out,        // [N, C, TT, 16, 16]
    int N)
{
    __shared__ float plane[PLANE_F];
    __shared__ int   idx_s[2 * MAX_N];

    const int c   = blockIdx.x;           // channel
    const int tt  = blockIdx.y;           // output time plane 0..17
    const int tid = threadIdx.x;

    // Stage indices once: inner-loop idx reads are uniform-address LDS
    // broadcasts (no per-iteration s_load latency chain).
    if (tid < 2 * N && tid < 2 * MAX_N) idx_s[tid] = active_idx[tid];

    if (tt >= PAD_T) {
        // Stage the full 128x128 plane x[c][tt-2] into LDS. 4 float4 loads
        // per thread; with 16 waves the whole 64KB is in flight at once ->
        // staging is BW-limited, not latency-limited.
        const float* __restrict__ src =
            x + ((size_t)c * T_DIM + (size_t)(tt - PAD_T)) * (size_t)(H_DIM * W_DIM);
        #pragma unroll
        for (int it = 0; it < (H_DIM * W_DIM) / (NTHREADS * 4); ++it) {  // 4 iters
            const int f   = (it * NTHREADS + tid) * 4;  // float index in plane
            const int r   = f >> 7;                     // 0..127
            const int col = f & 127;                    // multiple of 4 -> 16B aligned
            *(f4*)(&plane[r * S_LDS + col]) = *(const f4*)(src + f);
        }
    }
    __syncthreads();

    // Wave w handles n = w, w+16, ... ; its 64 lanes cover the 16x16 block
    // as (row = slot>>2, 4 cols starting at (slot&3)*4). Per iter per wave:
    // 1 uniform LDS idx read + 1 f4 LDS read + 1 global_store_dwordx4
    // (64 lanes x 16B = 1KB contiguous, full 128B lines).
    const int wid  = tid >> 6;
    const int slot = tid & 63;
    const int row  = slot >> 2;
    const int cg   = (slot & 3) << 2;     // column group start: 0,4,8,12

    const size_t nstride = (size_t)C_DIM * TT * 256;   // out stride between n's
    float* op = out + ((size_t)c * TT + tt) * 256 + row * 16 + cg
                    + (size_t)wid * nstride;

    if (tt >= PAD_T) {
        const float* pl = plane + row * S_LDS + cg;
        #pragma unroll 4
        for (int n = wid; n < N; n += NWAVES) {
            const int i0 = idx_s[2 * n];      // wave-uniform -> broadcast
            const int i1 = idx_s[2 * n + 1];
            f4 v = *(const f4l*)(pl + i0 * S_LDS + i1);   // 4B-aligned float4
            __builtin_nontemporal_store(v, (f4*)op);
            op += nstride * NWAVES;
        }
    } else {
        // tt < PAD_T: causal time padding -> zero planes.
        const f4 z = {0.f, 0.f, 0.f, 0.f};
        #pragma unroll 4
        for (int n = wid; n < N; n += NWAVES) {
            __builtin_nontemporal_store(z, (f4*)op);
            op += nstride * NWAVES;
        }
    }
}

extern "C" void kernel_launch(void* const* d_in, const int* in_sizes, int n_in,
                              void* d_out, int out_size, void* d_ws, size_t ws_size,
                              hipStream_t stream) {
    const float* x   = (const float*)d_in[0];
    const int*   idx = (const int*)d_in[1];
    float*       out = (float*)d_out;

    const int N = in_sizes[1] / 2;   // 128 active indices

    dim3 grid(C_DIM, TT);            // one workgroup per (c, tt) plane
    gather3d_plane<<<grid, dim3(NTHREADS), 0, stream>>>(x, idx, out, N);
}

// Round 4
// 396.937 us; speedup vs baseline: 1.0181x; 1.0134x over previous
//
#include <hip/hip_runtime.h>

// Gather3d sparse-mode constants (from reference)
#define C_DIM 128
#define T_DIM 16
#define H_DIM 128
#define W_DIM 128
#define PAD_T 2
#define TT (T_DIM + PAD_T)           // 18 output planes per (n,c)

// LDS plane layout: row stride 144 floats. 144 % 32 == 16 -> a wave's
// 16-row x 16-col f4 read footprint covers all 32 banks evenly.
// 128*144*4 = 73,728 B -> 2 workgroups / CU.
#define S_LDS 144
#define PLANE_F (H_DIM * S_LDS)      // 18432 floats
#define MAX_N 256                    // idx LDS capacity (harness: N=128)

#define NTHREADS 1024
#define NWAVES (NTHREADS / 64)       // 16

typedef float f4  __attribute__((ext_vector_type(4), aligned(16)));
typedef float f4l __attribute__((ext_vector_type(4), aligned(4)));  // LDS read at runtime 4B offset

// Grid is (tt fast, c slow): the ~512 concurrently-resident wgs then cover
// ALL 18 tt-planes of ~28 consecutive channels, so their combined output
// writes form ~500KB dense regions per n (out[n][c:c+28][:][:]) instead of
// 1KB chunks at 18KB stride -- DRAM page/channel locality for the NT-store
// stream approaches the sequential-fill pattern (which achieves 6.3 TB/s).
__global__ __launch_bounds__(NTHREADS, 8) void gather3d_plane(
    const float* __restrict__ x,          // [C, T, H, W]
    const int*   __restrict__ active_idx, // [N, 2]
    float*       __restrict__ out,        // [N, C, TT, 16, 16]
    int N)
{
    __shared__ float plane[PLANE_F];
    __shared__ int   idx_s[2 * MAX_N];

    const int tt  = blockIdx.x;           // output time plane 0..17 (fast dim)
    const int c   = blockIdx.y;           // channel (slow dim)
    const int tid = threadIdx.x;

    const int wid  = tid >> 6;
    const int slot = tid & 63;
    const int row  = slot >> 2;
    const int cg   = (slot & 3) << 2;     // column group start: 0,4,8,12

    const size_t nstride = (size_t)C_DIM * TT * 256;   // out stride between n's
    float* op = out + ((size_t)c * TT + tt) * 256 + row * 16 + cg
                    + (size_t)wid * nstride;

    if (tt < PAD_T) {
        // Causal time padding -> zero planes. No staging, no barrier needed.
        const f4 z = {0.f, 0.f, 0.f, 0.f};
        #pragma unroll 4
        for (int n = wid; n < N; n += NWAVES) {
            __builtin_nontemporal_store(z, (f4*)op);
            op += nstride * NWAVES;
        }
        return;
    }

    // Stage indices once: inner-loop idx reads are uniform-address LDS
    // broadcasts (no per-iteration s_load latency chain).
    if (tid < 2 * N && tid < 2 * MAX_N) idx_s[tid] = active_idx[tid];

    // Stage the full 128x128 plane x[c][tt-2] into LDS. Dense float4 loads:
    // x is read exactly once, fully coalesced, zero line amplification.
    {
        const float* __restrict__ src =
            x + ((size_t)c * T_DIM + (size_t)(tt - PAD_T)) * (size_t)(H_DIM * W_DIM);
        #pragma unroll
        for (int it = 0; it < (H_DIM * W_DIM) / (NTHREADS * 4); ++it) {  // 4 iters
            const int f   = (it * NTHREADS + tid) * 4;  // float index in plane
            const int r   = f >> 7;                     // 0..127
            const int col = f & 127;                    // multiple of 4 -> 16B aligned
            *(f4*)(&plane[r * S_LDS + col]) = *(const f4*)(src + f);
        }
    }
    __syncthreads();

    // Wave w handles n = w, w+16, ... ; lanes cover the 16x16 block as
    // (row, 4-col group). Per iter per wave: 1 uniform LDS idx read +
    // 1 f4 LDS read + 1 global_store_dwordx4 (1KB contiguous, full lines).
    const float* pl = plane + row * S_LDS + cg;
    #pragma unroll 4
    for (int n = wid; n < N; n += NWAVES) {
        const int i0 = idx_s[2 * n];      // wave-uniform -> broadcast
        const int i1 = idx_s[2 * n + 1];
        f4 v = *(const f4l*)(pl + i0 * S_LDS + i1);   // 4B-aligned float4
        __builtin_nontemporal_store(v, (f4*)op);
        op += nstride * NWAVES;
    }
}

extern "C" void kernel_launch(void* const* d_in, const int* in_sizes, int n_in,
                              void* d_out, int out_size, void* d_ws, size_t ws_size,
                              hipStream_t stream) {
    const float* x   = (const float*)d_in[0];
    const int*   idx = (const int*)d_in[1];
    float*       out = (float*)d_out;

    const int N = in_sizes[1] / 2;   // 128 active indices

    dim3 grid(TT, C_DIM);            // tt fast, c slow (write locality)
    gather3d_plane<<<grid, dim3(NTHREADS), 0, stream>>>(x, idx, out, N);
}

// Round 5
// 392.287 us; speedup vs baseline: 1.0302x; 1.0119x over previous
//
#include <hip/hip_runtime.h>

// Gather3d sparse-mode constants (from reference)
#define C_DIM 128
#define T_DIM 16
#define H_DIM 128
#define W_DIM 128
#define PAD_T 2
#define TT (T_DIM + PAD_T)           // 18 output planes per (n,c)

// LDS plane layout: row stride 144 floats. 144 % 32 == 16 -> a wave's
// 16-row x 16-col f4 read footprint covers all 32 banks evenly.
// 128*144*4 = 73,728 B -> 2 workgroups / CU.
#define S_LDS 144
#define PLANE_F (H_DIM * S_LDS)      // 18432 floats
#define MAX_N 256                    // idx LDS capacity (harness: N=128)

#define NTHREADS 1024
#define NWAVES (NTHREADS / 64)       // 16

typedef float f4  __attribute__((ext_vector_type(4), aligned(16)));
typedef float f4l __attribute__((ext_vector_type(4), aligned(4)));  // LDS read at runtime 4B offset

// R5 isolation experiment: identical to R4 except PLAIN stores instead of
// __builtin_nontemporal_store. NT bypasses L2/L3 write-combining -> scattered
// 1KB chunks stream to DRAM with poor page batching (~2.4 TB/s observed).
// Plain stores drain through the 32MB L2 write-back path like the poison
// fill does (6.3 TB/s). L3 pollution by writes is free here: every x line
// is dead after its single staged read.
__global__ __launch_bounds__(NTHREADS, 8) void gather3d_plane(
    const float* __restrict__ x,          // [C, T, H, W]
    const int*   __restrict__ active_idx, // [N, 2]
    float*       __restrict__ out,        // [N, C, TT, 16, 16]
    int N)
{
    __shared__ float plane[PLANE_F];
    __shared__ int   idx_s[2 * MAX_N];

    const int tt  = blockIdx.x;           // output time plane 0..17 (fast dim)
    const int c   = blockIdx.y;           // channel (slow dim)
    const int tid = threadIdx.x;

    const int wid  = tid >> 6;
    const int slot = tid & 63;
    const int row  = slot >> 2;
    const int cg   = (slot & 3) << 2;     // column group start: 0,4,8,12

    const size_t nstride = (size_t)C_DIM * TT * 256;   // out stride between n's
    float* op = out + ((size_t)c * TT + tt) * 256 + row * 16 + cg
                    + (size_t)wid * nstride;

    if (tt < PAD_T) {
        // Causal time padding -> zero planes. No staging, no barrier needed.
        const f4 z = {0.f, 0.f, 0.f, 0.f};
        #pragma unroll 4
        for (int n = wid; n < N; n += NWAVES) {
            *(f4*)op = z;
            op += nstride * NWAVES;
        }
        return;
    }

    // Stage indices once: inner-loop idx reads are uniform-address LDS
    // broadcasts (no per-iteration s_load latency chain).
    if (tid < 2 * N && tid < 2 * MAX_N) idx_s[tid] = active_idx[tid];

    // Stage the full 128x128 plane x[c][tt-2] into LDS. Dense float4 loads:
    // x is read exactly once, fully coalesced, zero line amplification.
    {
        const float* __restrict__ src =
            x + ((size_t)c * T_DIM + (size_t)(tt - PAD_T)) * (size_t)(H_DIM * W_DIM);
        #pragma unroll
        for (int it = 0; it < (H_DIM * W_DIM) / (NTHREADS * 4); ++it) {  // 4 iters
            const int f   = (it * NTHREADS + tid) * 4;  // float index in plane
            const int r   = f >> 7;                     // 0..127
            const int col = f & 127;                    // multiple of 4 -> 16B aligned
            *(f4*)(&plane[r * S_LDS + col]) = *(const f4*)(src + f);
        }
    }
    __syncthreads();

    // Wave w handles n = w, w+16, ... ; lanes cover the 16x16 block as
    // (row, 4-col group). Per iter per wave: 1 uniform LDS idx read +
    // 1 f4 LDS read + 1 global_store_dwordx4 (1KB contiguous, full lines).
    const float* pl = plane + row * S_LDS + cg;
    #pragma unroll 4
    for (int n = wid; n < N; n += NWAVES) {
        const int i0 = idx_s[2 * n];      // wave-uniform -> broadcast
        const int i1 = idx_s[2 * n + 1];
        f4 v = *(const f4l*)(pl + i0 * S_LDS + i1);   // 4B-aligned float4
        *(f4*)op = v;
        op += nstride * NWAVES;
    }
}

extern "C" void kernel_launch(void* const* d_in, const int* in_sizes, int n_in,
                              void* d_out, int out_size, void* d_ws, size_t ws_size,
                              hipStream_t stream) {
    const float* x   = (const float*)d_in[0];
    const int*   idx = (const int*)d_in[1];
    float*       out = (float*)d_out;

    const int N = in_sizes[1] / 2;   // 128 active indices

    dim3 grid(TT, C_DIM);            // tt fast, c slow (write locality)
    gather3d_plane<<<grid, dim3(NTHREADS), 0, stream>>>(x, idx, out, N);
}